// Round 10
// baseline (135.252 us; speedup 1.0000x reference)
//
#include <hip/hip_runtime.h>
#include <math.h>

// Problem constants (match reference)
#define MB 8      // batch
#define MM 384    // checks
#define NN 1536   // variables
#define LL 20     // layers
#define RW 8      // row weight of H
#define HE 4      // edges per thread (half row)
#define NE (MM*RW)  // 3072 edges
#define NT 768    // bp block size (2 threads per check row)
#define VP 12     // max column degree supported (validated: never hit)
#define VG 3      // VP/4 float4 groups

#define LOG2E 1.44269504f
#define LN2   0.69314718f

// Soft barrier: LDS visibility only (s_waitcnt lgkmcnt(0) + s_barrier).
// Deliberately does NOT drain vmcnt — global prefetches stay in flight.
#define SOFT_BAR() asm volatile("s_waitcnt lgkmcnt(0)\n\ts_barrier" ::: "memory")

// Lane xor-1 exchange via DPP quad_perm(1,0,3,2): pure VALU.
static __device__ __forceinline__ float dpp_xor1(float x) {
    return __int_as_float(
        __builtin_amdgcn_mov_dpp(__float_as_int(x), 0xB1, 0xF, 0xF, true));
}

// ---------------------------------------------------------------------------
// Fused setup: one block (256 thr = 4 waves) per check row.
// R10: slot positions computed DETERMINISTICALLY (column prefix-count via a
// 32-lane strided scan of H's column), eliminating the gcnt atomics and the
// hipMemsetAsync dispatch entirely.  gdeg is written redundantly by every
// owning block (identical values — benign).  Outputs identical in meaning
// to R8; slot order is now row-ordered instead of atomic-arrival-ordered.
// ---------------------------------------------------------------------------
__global__ __launch_bounds__(256) void setup_kernel(
    const float* __restrict__ H,
    const float* __restrict__ llrs,
    const float* __restrict__ w_llr,
    const float* __restrict__ w_de,
    const float* __restrict__ marg_de,
    int*   __restrict__ col_pack,
    float* __restrict__ base_e,
    float* __restrict__ wde_e,
    float* __restrict__ marg_e,
    int*   __restrict__ gdeg,
    float* __restrict__ out) {
    const int m = blockIdx.x;
    const int t = threadIdx.x;
    const int w = t >> 6, lane = t & 63;
    __shared__ int s_qcol[4][RW];
    __shared__ int s_qcnt[4];
    __shared__ int s_col[RW];

    // ---- pass 1: find the RW nonzero columns of row m (unchanged) ----
    const float* row = H + (size_t)m * NN;
    int count = 0;
    for (int c0 = w * 384; c0 < (w + 1) * 384; c0 += 64) {
        float v = row[c0 + lane];
        unsigned long long mask = __ballot(v != 0.0f);
        if (v != 0.0f) {
            int pos = count + (int)__popcll(mask & ((1ull << lane) - 1ull));
            if (pos < RW) s_qcol[w][pos] = c0 + lane;
        }
        count += (int)__popcll(mask);
    }
    if (lane == 0) s_qcnt[w] = (count < RW) ? count : RW;
    __syncthreads();
    if (t == 0) {
        int off = 0;
        for (int q = 0; q < 4; ++q)
            for (int i = 0; i < s_qcnt[q]; ++i) {
                if (off < RW) s_col[off] = s_qcol[q][i];
                ++off;
            }
    }
    __syncthreads();

    // ---- pass 2: deterministic pos + column degree (32 lanes per column) ----
    {
        const int g = t >> 5;            // owned-column group 0..7
        const int j = t & 31;            // lane within group
        const int c = s_col[g];
        int cnt_lt = 0, cnt_all = 0;
        #pragma unroll 4
        for (int mp = j; mp < MM; mp += 32) {
            int nz = (H[(size_t)mp * NN + c] != 0.0f) ? 1 : 0;
            cnt_all += nz;
            cnt_lt  += (mp < m) ? nz : 0;
        }
        #pragma unroll
        for (int off = 16; off > 0; off >>= 1) {
            cnt_all += __shfl_down(cnt_all, off, 32);
            cnt_lt  += __shfl_down(cnt_lt,  off, 32);
        }
        if (j == 0) {
            int pos = cnt_lt;
            if (pos >= VP) pos = VP - 1;   // clamp (validated: never hit)
            // bank-conflict swizzle of the intra-group slot position
            int ps = (pos & ~3) | ((pos & 3) ^ ((c >> 3) & 3));
            col_pack[m * RW + g] = c | (ps << 16);
            // messages live in log2 domain -> marg weight carries ln2
            marg_e[m * RW + g] = marg_de[m * NN + c] * LN2;
            gdeg[c] = cnt_all;             // duplicate identical writes: benign
        }
    }
    if (m == 0 && t == 0) out[0] = 0.0f;

    // ---- pass 3: edge-ordered weight streams (uses s_col only) ----
    for (int idx = t; idx < LL * RW; idx += 256) {
        int l = idx >> 3;
        int k = idx & 7;
        int c = s_col[k];
        wde_e[l * NE + m * RW + k] = w_de[(size_t)l * MM * NN + (size_t)m * NN + c];
        // base in log2 domain
        base_e[l * NE + m * RW + k] = llrs[c] * w_llr[l * NN + c] * LOG2E;
    }
}

// ===========================================================================
// One full layer body (x2-unrolled prefetch-buffer swap) — bit-for-bit R8
// (best verified: e2e 131.8).  Check thread writes TWO pre-weighted copies:
//   s_cW[esl] = nm * wde_e[l+1][edge]   (next gather's S term)
//   s_cM[esl] = nm * marg_e[edge]       (belief term)
// Owner gather is pure slot-sum (adds only, no weight regs, no fetch).
// ===========================================================================
#define LAYER_BODY(lv, WNC, WNN, BN)                                          \
{                                                                             \
    /* prefetch: wde_e[lv+2] and base_e[lv+1] (stay in flight) */             \
    {                                                                         \
        int la2 = ((lv) + 2 < LL) ? ((lv) + 2) : (LL - 1);                    \
        const float4 w4 = ((const float4*)(wde_e_g + la2 * NE))[t];           \
        WNN[0]=w4.x; WNN[1]=w4.y; WNN[2]=w4.z; WNN[3]=w4.w;                   \
        int lb = ((lv) + 1 < LL) ? ((lv) + 1) : (LL - 1);                     \
        const float4 bp4 = ((const float4*)(base_e_g + lb * NE))[t];          \
        BN[0]=bp4.x; BN[1]=bp4.y; BN[2]=bp4.z; BN[3]=bp4.w;                   \
    }                                                                         \
    /* phase A: owner slot-sums; group-0 belief quad held for phase B */      \
    float4 m0a = ((const float4*)s_cM)[t];                                    \
    float4 m0b = ((const float4*)s_cM)[t + NT];                               \
    float belx0 = bias[0], belx1 = bias[1];                                   \
    {                                                                         \
        float4 w0a = ((const float4*)s_cW)[t];                                \
        float4 w0b = ((const float4*)s_cW)[t + NT];                           \
        float S0 = (w0a.x + w0a.y) + (w0a.z + w0a.w);                         \
        float S1 = (w0b.x + w0b.y) + (w0b.z + w0b.w);                         \
        if (deg0 > 4) {                                                       \
            float4 a = ((const float4*)s_cW)[NN + t];                         \
            float4 q = ((const float4*)s_cM)[NN + t];                         \
            S0    += (a.x + a.y) + (a.z + a.w);                               \
            belx0 += (q.x + q.y) + (q.z + q.w);                               \
        }                                                                     \
        if (deg1 > 4) {                                                       \
            float4 a = ((const float4*)s_cW)[NN + t + NT];                    \
            float4 q = ((const float4*)s_cM)[NN + t + NT];                    \
            S1    += (a.x + a.y) + (a.z + a.w);                               \
            belx1 += (q.x + q.y) + (q.z + q.w);                               \
        }                                                                     \
        if (deg0 > 8) {                                                       \
            float4 a = ((const float4*)s_cW)[2 * NN + t];                     \
            float4 q = ((const float4*)s_cM)[2 * NN + t];                     \
            S0    += (a.x + a.y) + (a.z + a.w);                               \
            belx0 += (q.x + q.y) + (q.z + q.w);                               \
        }                                                                     \
        if (deg1 > 8) {                                                       \
            float4 a = ((const float4*)s_cW)[2 * NN + t + NT];                \
            float4 q = ((const float4*)s_cM)[2 * NN + t + NT];                \
            S1    += (a.x + a.y) + (a.z + a.w);                               \
            belx1 += (q.x + q.y) + (q.z + q.w);                               \
        }                                                                     \
        s_S[t]      = S0;                                                     \
        s_S[t + NT] = S1;                                                     \
    }                                                                         \
    SOFT_BAR();   /* barrier A: s_S visible; old s_cW/s_cM consumed */        \
    {                                                                         \
        /* issue the scattered s_S reads first */                             \
        float ss[HE];                                                         \
        _Pragma("unroll")                                                     \
        for (int k = 0; k < HE; ++k) ss[k] = s_S[col[k]];                     \
        /* filler: group-0 belief + loss for layer lv-1 */                    \
        if ((lv) > 0) {                                                       \
            const float rr = rhos[(lv) - 1];                                  \
            float bel0 = belx0 + (m0a.x + m0a.y) + (m0a.z + m0a.w);           \
            float bel1 = belx1 + (m0b.x + m0b.y) + (m0b.z + m0b.w);           \
            float sp0 = fmaxf(bel0, 0.0f) + __logf(1.0f + __expf(-fabsf(bel0))); \
            float sp1 = fmaxf(bel1, 0.0f) + __logf(1.0f + __expf(-fabsf(bel1))); \
            loss += rr * ((sp0 - omeg[0] * bel0) + (sp1 - omeg[1] * bel1));   \
        }                                                                     \
        const float rw_ = res_w[(lv)];                                        \
        float d[HE];                                                          \
        _Pragma("unroll")                                                     \
        for (int k = 0; k < HE; ++k) {                                        \
            float te = tm[k] + ss[k];                /* log2 domain */        \
            float e  = __builtin_amdgcn_exp2f(te);                            \
            float dd = 1.0f - 2.0f * __builtin_amdgcn_rcpf(e + 1.0f);         \
            dd = fminf(fmaxf(dd, -1.0f), 1.0f);                               \
            if (dd == 0.0f) dd = 1.0f;                                        \
            d[k] = dd;                                                        \
        }                                                                     \
        float p4 = (d[0] * d[1]) * (d[2] * d[3]);                             \
        float P  = p4 * dpp_xor1(p4);    /* full 8-edge row product */        \
        _Pragma("unroll")                                                     \
        for (int k = 0; k < HE; ++k) {                                        \
            /* 2*atanh(P/d) = log((d+P)/(d-P)); exact, no exclusion prods */  \
            float la  = __builtin_amdgcn_logf(fabsf(d[k] + P));               \
            float lb2 = __builtin_amdgcn_logf(fabsf(d[k] - P));               \
            float nm = sgn * (la - lb2) + rw_ * msg[k];   /* log2 domain */   \
            msg[k] = nm;                                                      \
            s_cW[esl[k]] = nm * WNC[k];   /* pre-weighted for next S */       \
            s_cM[esl[k]] = nm * me[k];    /* pre-weighted for beliefs */      \
        }                                                                     \
        /* prefold next layer's te base (off critical path) */                \
        _Pragma("unroll")                                                     \
        for (int k = 0; k < HE; ++k) tm[k] = BN[k] - msg[k];                  \
    }                                                                         \
    SOFT_BAR();   /* barrier B: s_cW/s_cM visible for next gather */          \
}

// ---------------------------------------------------------------------------
// Main BP kernel: 8 blocks, 768 threads = 2 per check row (4 edges each).
// Zero atomics; dual pre-weighted swizzled CSC exchange; 2 SOFT barriers
// per layer; x2 unroll; degree-gated slot-sum gather; DPP row product;
// log2-domain messages; (d+P)/(d-P) self-exclusion.  (= R8, best verified)
// ---------------------------------------------------------------------------
__global__ __launch_bounds__(NT) void bp_kernel(
    const float* __restrict__ synd,       // (B,M,1)
    const float* __restrict__ errors,     // (B,N)
    const float* __restrict__ llrs,       // (N)
    const float* __restrict__ marg_llr,   // (N)
    const float* __restrict__ res_w,      // (L)
    const float* __restrict__ rhos,       // (L)
    const int*   __restrict__ col_pack,   // (E)  c | pos<<16 (swizzled pos)
    const float* __restrict__ base_e_g,   // (L,E)  log2-scaled
    const float* __restrict__ wde_e_g,    // (L,E)  edge-ordered
    const float* __restrict__ marg_e_g,   // (E)    edge-ordered, ln2-scaled
    const int*   __restrict__ gdeg,       // (N)  column degrees
    float* __restrict__ out) {

    __shared__ float s_cW[NN * VP];       // 72 KB  wde-weighted messages
    __shared__ float s_cM[NN * VP];       // 72 KB  marg-weighted messages
    __shared__ float s_S[NN];             // 6 KB   variable sums
    __shared__ float s_red[12];

    const int b = blockIdx.x;
    const int t = threadIdx.x;
    const int m = t >> 1;        // check row

    // ---- per-edge register state ----
    int col[HE], esl[HE];
    {
        const int4 cp = ((const int4*)col_pack)[t];
        int v[HE] = {cp.x, cp.y, cp.z, cp.w};
        #pragma unroll
        for (int k = 0; k < HE; ++k) {
            int c = v[k] & 0xFFFF, pos = v[k] >> 16;
            col[k] = c;
            esl[k] = ((pos >> 2) * NN + c) * 4 + (pos & 3);
        }
    }
    float msg[HE] = {0.0f, 0.0f, 0.0f, 0.0f};
    const float sgn = 1.0f - 2.0f * synd[b * MM + m];

    // ---- owned-variable state ----
    const int deg0 = gdeg[t];
    const int deg1 = gdeg[t + NT];
    float bias[2], omeg[2];
    #pragma unroll
    for (int i = 0; i < 2; ++i) {
        int n = t + i * NT;
        bias[i] = llrs[n] * marg_llr[n];
        omeg[i] = 1.0f - errors[b * NN + n];
    }

    // ---- static edge weights (marg) + first wde prefetch buffer ----
    float me[HE];
    {
        const float4 m4 = ((const float4*)marg_e_g)[t];
        me[0] = m4.x; me[1] = m4.y; me[2] = m4.z; me[3] = m4.w;
    }
    float wnA[HE], wnB[HE];
    {
        const float4 w4 = ((const float4*)(wde_e_g + NE))[t];   // wde_e[1]
        wnA[0] = w4.x; wnA[1] = w4.y; wnA[2] = w4.z; wnA[3] = w4.w;
    }
    float bcA[HE], bcB[HE];
    float tm[HE];
    {
        const float4 bp4 = ((const float4*)base_e_g)[t];   // layer 0
        bcA[0] = bp4.x; bcA[1] = bp4.y; bcA[2] = bp4.z; bcA[3] = bp4.w;
        #pragma unroll
        for (int k = 0; k < HE; ++k) tm[k] = bcA[k];       // msg == 0
    }

    // ---- zero both exchange arrays (padding slots stay 0 forever) ----
    #pragma unroll
    for (int j = 0; j < 6; ++j) {
        ((float4*)s_cW)[j * NT + t] = make_float4(0.f, 0.f, 0.f, 0.f);
        ((float4*)s_cM)[j * NT + t] = make_float4(0.f, 0.f, 0.f, 0.f);
    }

    float loss = 0.0f;
    __syncthreads();

    // ---- layer loop, unrolled x2 with A/B prefetch-buffer swap ----
    for (int l = 0; l < LL; l += 2) {
        LAYER_BODY(l,     wnA, wnB, bcB);
        LAYER_BODY(l + 1, wnB, wnA, bcA);
    }

    // tail: loss for the last layer (degree-gated slot-sum, bit-exact)
    {
        const float rr = rhos[LL - 1];
        float bel0 = bias[0], bel1 = bias[1];
        {
            float4 a = ((const float4*)s_cM)[t];
            float4 c4 = ((const float4*)s_cM)[t + NT];
            bel0 += (a.x + a.y) + (a.z + a.w);
            bel1 += (c4.x + c4.y) + (c4.z + c4.w);
        }
        if (deg0 > 4) {
            float4 a = ((const float4*)s_cM)[NN + t];
            bel0 += (a.x + a.y) + (a.z + a.w);
        }
        if (deg1 > 4) {
            float4 c4 = ((const float4*)s_cM)[NN + t + NT];
            bel1 += (c4.x + c4.y) + (c4.z + c4.w);
        }
        if (deg0 > 8) {
            float4 a = ((const float4*)s_cM)[2 * NN + t];
            bel0 += (a.x + a.y) + (a.z + a.w);
        }
        if (deg1 > 8) {
            float4 c4 = ((const float4*)s_cM)[2 * NN + t + NT];
            bel1 += (c4.x + c4.y) + (c4.z + c4.w);
        }
        float sp0 = fmaxf(bel0, 0.0f) + __logf(1.0f + __expf(-fabsf(bel0)));
        float sp1 = fmaxf(bel1, 0.0f) + __logf(1.0f + __expf(-fabsf(bel1)));
        loss += rr * ((sp0 - omeg[0] * bel0) + (sp1 - omeg[1] * bel1));
    }

    // ---- block-wide loss reduction (12 waves) ----
    #pragma unroll
    for (int off = 32; off > 0; off >>= 1)
        loss += __shfl_down(loss, off, 64);
    int wave = t >> 6, lane = t & 63;
    if (lane == 0) s_red[wave] = loss;
    __syncthreads();
    if (t == 0) {
        float tot = 0.0f;
        #pragma unroll
        for (int w = 0; w < 12; ++w) tot += s_red[w];
        atomicAdd(out, tot * (1.0f / (float)MB));
    }
}

// ---------------------------------------------------------------------------
extern "C" void kernel_launch(void* const* d_in, const int* in_sizes, int n_in,
                              void* d_out, int out_size, void* d_ws, size_t ws_size,
                              hipStream_t stream) {
    const float* synd     = (const float*)d_in[0];
    const float* errors   = (const float*)d_in[1];
    const float* H        = (const float*)d_in[2];
    const float* llrs     = (const float*)d_in[3];
    const float* w_de     = (const float*)d_in[4];
    const float* w_llr    = (const float*)d_in[5];
    const float* marg_de  = (const float*)d_in[6];
    const float* marg_llr = (const float*)d_in[7];
    const float* res_w    = (const float*)d_in[8];
    const float* rhos     = (const float*)d_in[9];
    float* out = (float*)d_out;

    float* wde_e   = (float*)d_ws;
    float* base_e  = wde_e + (size_t)LL * NE;
    float* marg_e  = base_e + (size_t)LL * NE;
    int*   gdeg    = (int*)(marg_e + NE);
    int*   col_pack= (int*)(gdeg + NN);

    // No memset: setup computes slot positions & degrees deterministically.
    setup_kernel<<<MM, 256, 0, stream>>>(H, llrs, w_llr, w_de, marg_de,
                                         col_pack, base_e, wde_e, marg_e,
                                         gdeg, out);
    bp_kernel<<<MB, NT, 0, stream>>>(synd, errors, llrs, marg_llr, res_w, rhos,
                                     col_pack, base_e, wde_e, marg_e, gdeg, out);
}

// Round 11
// 132.076 us; speedup vs baseline: 1.0240x; 1.0240x over previous
//
#include <hip/hip_runtime.h>
#include <math.h>

// Problem constants (match reference)
#define MB 8      // batch
#define MM 384    // checks
#define NN 1536   // variables
#define LL 20     // layers
#define RW 8      // row weight of H
#define HE 4      // edges per thread (half row)
#define NE (MM*RW)  // 3072 edges
#define NT 768    // bp block size (2 threads per check row)
#define VP 12     // max column degree supported (validated: never hit)
#define VG 3      // VP/4 float4 groups

#define LOG2E 1.44269504f
#define LN2   0.69314718f

// Soft barrier: LDS visibility only (s_waitcnt lgkmcnt(0) + s_barrier).
// Deliberately does NOT drain vmcnt — global prefetches stay in flight.
#define SOFT_BAR() asm volatile("s_waitcnt lgkmcnt(0)\n\ts_barrier" ::: "memory")

// Lane xor-1 exchange via DPP quad_perm(1,0,3,2): pure VALU.
static __device__ __forceinline__ float dpp_xor1(float x) {
    return __int_as_float(
        __builtin_amdgcn_mov_dpp(__float_as_int(x), 0xB1, 0xF, 0xF, true));
}

// ---------------------------------------------------------------------------
// Fused setup: one block (256 thr = 4 waves) per check row (exact R8:
// edge-ordered weights only; log2-domain base; ln2-scaled marg; atomic
// slot assignment with memset'd gcnt — measured cheaper than the
// deterministic prefix-scan variant, R10 post-mortem).
// ---------------------------------------------------------------------------
__global__ __launch_bounds__(256) void setup_kernel(
    const float* __restrict__ H,
    const float* __restrict__ llrs,
    const float* __restrict__ w_llr,
    const float* __restrict__ w_de,
    const float* __restrict__ marg_de,
    int*   __restrict__ col_pack,
    float* __restrict__ base_e,
    float* __restrict__ wde_e,
    float* __restrict__ marg_e,
    int*   __restrict__ gcnt,
    float* __restrict__ out) {
    const int m = blockIdx.x;
    const int t = threadIdx.x;
    const int w = t >> 6, lane = t & 63;
    __shared__ int s_qcol[4][RW];
    __shared__ int s_qcnt[4];
    __shared__ int s_col[RW];

    const float* row = H + (size_t)m * NN;
    int count = 0;
    for (int c0 = w * 384; c0 < (w + 1) * 384; c0 += 64) {
        float v = row[c0 + lane];
        unsigned long long mask = __ballot(v != 0.0f);
        if (v != 0.0f) {
            int pos = count + (int)__popcll(mask & ((1ull << lane) - 1ull));
            if (pos < RW) s_qcol[w][pos] = c0 + lane;
        }
        count += (int)__popcll(mask);
    }
    if (lane == 0) s_qcnt[w] = (count < RW) ? count : RW;
    __syncthreads();
    if (t == 0) {
        int off = 0;
        for (int q = 0; q < 4; ++q)
            for (int i = 0; i < s_qcnt[q]; ++i) {
                if (off < RW) s_col[off] = s_qcol[q][i];
                ++off;
            }
    }
    __syncthreads();

    if (t < RW) {
        int c = s_col[t];
        int pos = atomicAdd(&gcnt[c], 1);
        if (pos >= VP) pos = VP - 1;   // clamp (validated: never hit)
        // bank-conflict swizzle of the intra-group slot position
        int ps = (pos & ~3) | ((pos & 3) ^ ((c >> 3) & 3));
        col_pack[m * RW + t] = c | (ps << 16);
        // messages live in log2 domain -> marg weight carries ln2
        marg_e[m * RW + t] = marg_de[m * NN + c] * LN2;
    }
    if (m == 0 && t == 0) out[0] = 0.0f;
    __syncthreads();

    for (int idx = t; idx < LL * RW; idx += 256) {
        int l = idx >> 3;
        int k = idx & 7;
        int c = s_col[k];
        wde_e[l * NE + m * RW + k] = w_de[(size_t)l * MM * NN + (size_t)m * NN + c];
        // base in log2 domain
        base_e[l * NE + m * RW + k] = llrs[c] * w_llr[l * NN + c] * LOG2E;
    }
}

// ===========================================================================
// One full layer body (x2-unrolled prefetch-buffer swap) — exact R8
// (best verified: e2e 131.8).  Check thread writes TWO pre-weighted copies:
//   s_cW[esl] = nm * wde_e[l+1][edge]   (next gather's S term)
//   s_cM[esl] = nm * marg_e[edge]       (belief term)
// Owner gather is pure slot-sum (adds only, no weight regs, no fetch).
// Per-layer global traffic: 2 coalesced float4/thread (wde_e, base_e).
// ===========================================================================
#define LAYER_BODY(lv, WNC, WNN, BN)                                          \
{                                                                             \
    /* prefetch: wde_e[lv+2] and base_e[lv+1] (stay in flight) */             \
    {                                                                         \
        int la2 = ((lv) + 2 < LL) ? ((lv) + 2) : (LL - 1);                    \
        const float4 w4 = ((const float4*)(wde_e_g + la2 * NE))[t];           \
        WNN[0]=w4.x; WNN[1]=w4.y; WNN[2]=w4.z; WNN[3]=w4.w;                   \
        int lb = ((lv) + 1 < LL) ? ((lv) + 1) : (LL - 1);                     \
        const float4 bp4 = ((const float4*)(base_e_g + lb * NE))[t];          \
        BN[0]=bp4.x; BN[1]=bp4.y; BN[2]=bp4.z; BN[3]=bp4.w;                   \
    }                                                                         \
    /* phase A: owner slot-sums; group-0 belief quad held for phase B */      \
    float4 m0a = ((const float4*)s_cM)[t];                                    \
    float4 m0b = ((const float4*)s_cM)[t + NT];                               \
    float belx0 = bias[0], belx1 = bias[1];                                   \
    {                                                                         \
        float4 w0a = ((const float4*)s_cW)[t];                                \
        float4 w0b = ((const float4*)s_cW)[t + NT];                           \
        float S0 = (w0a.x + w0a.y) + (w0a.z + w0a.w);                         \
        float S1 = (w0b.x + w0b.y) + (w0b.z + w0b.w);                         \
        if (deg0 > 4) {                                                       \
            float4 a = ((const float4*)s_cW)[NN + t];                         \
            float4 q = ((const float4*)s_cM)[NN + t];                         \
            S0    += (a.x + a.y) + (a.z + a.w);                               \
            belx0 += (q.x + q.y) + (q.z + q.w);                               \
        }                                                                     \
        if (deg1 > 4) {                                                       \
            float4 a = ((const float4*)s_cW)[NN + t + NT];                    \
            float4 q = ((const float4*)s_cM)[NN + t + NT];                    \
            S1    += (a.x + a.y) + (a.z + a.w);                               \
            belx1 += (q.x + q.y) + (q.z + q.w);                               \
        }                                                                     \
        if (deg0 > 8) {                                                       \
            float4 a = ((const float4*)s_cW)[2 * NN + t];                     \
            float4 q = ((const float4*)s_cM)[2 * NN + t];                     \
            S0    += (a.x + a.y) + (a.z + a.w);                               \
            belx0 += (q.x + q.y) + (q.z + q.w);                               \
        }                                                                     \
        if (deg1 > 8) {                                                       \
            float4 a = ((const float4*)s_cW)[2 * NN + t + NT];                \
            float4 q = ((const float4*)s_cM)[2 * NN + t + NT];                \
            S1    += (a.x + a.y) + (a.z + a.w);                               \
            belx1 += (q.x + q.y) + (q.z + q.w);                               \
        }                                                                     \
        s_S[t]      = S0;                                                     \
        s_S[t + NT] = S1;                                                     \
    }                                                                         \
    SOFT_BAR();   /* barrier A: s_S visible; old s_cW/s_cM consumed */        \
    {                                                                         \
        /* issue the scattered s_S reads first */                             \
        float ss[HE];                                                         \
        _Pragma("unroll")                                                     \
        for (int k = 0; k < HE; ++k) ss[k] = s_S[col[k]];                     \
        /* filler: group-0 belief + loss for layer lv-1 */                    \
        if ((lv) > 0) {                                                       \
            const float rr = rhos[(lv) - 1];                                  \
            float bel0 = belx0 + (m0a.x + m0a.y) + (m0a.z + m0a.w);           \
            float bel1 = belx1 + (m0b.x + m0b.y) + (m0b.z + m0b.w);           \
            float sp0 = fmaxf(bel0, 0.0f) + __logf(1.0f + __expf(-fabsf(bel0))); \
            float sp1 = fmaxf(bel1, 0.0f) + __logf(1.0f + __expf(-fabsf(bel1))); \
            loss += rr * ((sp0 - omeg[0] * bel0) + (sp1 - omeg[1] * bel1));   \
        }                                                                     \
        const float rw_ = res_w[(lv)];                                        \
        float d[HE];                                                          \
        _Pragma("unroll")                                                     \
        for (int k = 0; k < HE; ++k) {                                        \
            float te = tm[k] + ss[k];                /* log2 domain */        \
            float e  = __builtin_amdgcn_exp2f(te);                            \
            float dd = 1.0f - 2.0f * __builtin_amdgcn_rcpf(e + 1.0f);         \
            dd = fminf(fmaxf(dd, -1.0f), 1.0f);                               \
            if (dd == 0.0f) dd = 1.0f;                                        \
            d[k] = dd;                                                        \
        }                                                                     \
        float p4 = (d[0] * d[1]) * (d[2] * d[3]);                             \
        float P  = p4 * dpp_xor1(p4);    /* full 8-edge row product */        \
        _Pragma("unroll")                                                     \
        for (int k = 0; k < HE; ++k) {                                        \
            /* 2*atanh(P/d) = log((d+P)/(d-P)); exact, no exclusion prods */  \
            float la  = __builtin_amdgcn_logf(fabsf(d[k] + P));               \
            float lb2 = __builtin_amdgcn_logf(fabsf(d[k] - P));               \
            float nm = sgn * (la - lb2) + rw_ * msg[k];   /* log2 domain */   \
            msg[k] = nm;                                                      \
            s_cW[esl[k]] = nm * WNC[k];   /* pre-weighted for next S */       \
            s_cM[esl[k]] = nm * me[k];    /* pre-weighted for beliefs */      \
        }                                                                     \
        /* prefold next layer's te base (off critical path) */                \
        _Pragma("unroll")                                                     \
        for (int k = 0; k < HE; ++k) tm[k] = BN[k] - msg[k];                  \
    }                                                                         \
    SOFT_BAR();   /* barrier B: s_cW/s_cM visible for next gather */          \
}

// ---------------------------------------------------------------------------
// Main BP kernel: 8 blocks, 768 threads = 2 per check row (4 edges each).
// Zero atomics; dual pre-weighted swizzled CSC exchange; 2 SOFT barriers
// per layer; x2 unroll; degree-gated slot-sum gather; DPP row product;
// log2-domain messages; (d+P)/(d-P) self-exclusion.  (= R8, best verified)
// ---------------------------------------------------------------------------
__global__ __launch_bounds__(NT) void bp_kernel(
    const float* __restrict__ synd,       // (B,M,1)
    const float* __restrict__ errors,     // (B,N)
    const float* __restrict__ llrs,       // (N)
    const float* __restrict__ marg_llr,   // (N)
    const float* __restrict__ res_w,      // (L)
    const float* __restrict__ rhos,       // (L)
    const int*   __restrict__ col_pack,   // (E)  c | pos<<16 (swizzled pos)
    const float* __restrict__ base_e_g,   // (L,E)  log2-scaled
    const float* __restrict__ wde_e_g,    // (L,E)  edge-ordered
    const float* __restrict__ marg_e_g,   // (E)    edge-ordered, ln2-scaled
    const int*   __restrict__ gdeg,       // (N)  column degrees (= gcnt)
    float* __restrict__ out) {

    __shared__ float s_cW[NN * VP];       // 72 KB  wde-weighted messages
    __shared__ float s_cM[NN * VP];       // 72 KB  marg-weighted messages
    __shared__ float s_S[NN];             // 6 KB   variable sums
    __shared__ float s_red[12];

    const int b = blockIdx.x;
    const int t = threadIdx.x;
    const int m = t >> 1;        // check row

    // ---- per-edge register state ----
    int col[HE], esl[HE];
    {
        const int4 cp = ((const int4*)col_pack)[t];
        int v[HE] = {cp.x, cp.y, cp.z, cp.w};
        #pragma unroll
        for (int k = 0; k < HE; ++k) {
            int c = v[k] & 0xFFFF, pos = v[k] >> 16;
            col[k] = c;
            esl[k] = ((pos >> 2) * NN + c) * 4 + (pos & 3);
        }
    }
    float msg[HE] = {0.0f, 0.0f, 0.0f, 0.0f};
    const float sgn = 1.0f - 2.0f * synd[b * MM + m];

    // ---- owned-variable state ----
    const int deg0 = gdeg[t];
    const int deg1 = gdeg[t + NT];
    float bias[2], omeg[2];
    #pragma unroll
    for (int i = 0; i < 2; ++i) {
        int n = t + i * NT;
        bias[i] = llrs[n] * marg_llr[n];
        omeg[i] = 1.0f - errors[b * NN + n];
    }

    // ---- static edge weights (marg) + first wde prefetch buffer ----
    float me[HE];
    {
        const float4 m4 = ((const float4*)marg_e_g)[t];
        me[0] = m4.x; me[1] = m4.y; me[2] = m4.z; me[3] = m4.w;
    }
    float wnA[HE], wnB[HE];
    {
        const float4 w4 = ((const float4*)(wde_e_g + NE))[t];   // wde_e[1]
        wnA[0] = w4.x; wnA[1] = w4.y; wnA[2] = w4.z; wnA[3] = w4.w;
    }
    float bcA[HE], bcB[HE];
    float tm[HE];
    {
        const float4 bp4 = ((const float4*)base_e_g)[t];   // layer 0
        bcA[0] = bp4.x; bcA[1] = bp4.y; bcA[2] = bp4.z; bcA[3] = bp4.w;
        #pragma unroll
        for (int k = 0; k < HE; ++k) tm[k] = bcA[k];       // msg == 0
    }

    // ---- zero both exchange arrays (padding slots stay 0 forever) ----
    #pragma unroll
    for (int j = 0; j < 6; ++j) {
        ((float4*)s_cW)[j * NT + t] = make_float4(0.f, 0.f, 0.f, 0.f);
        ((float4*)s_cM)[j * NT + t] = make_float4(0.f, 0.f, 0.f, 0.f);
    }

    float loss = 0.0f;
    __syncthreads();

    // ---- layer loop, unrolled x2 with A/B prefetch-buffer swap ----
    for (int l = 0; l < LL; l += 2) {
        LAYER_BODY(l,     wnA, wnB, bcB);
        LAYER_BODY(l + 1, wnB, wnA, bcA);
    }

    // tail: loss for the last layer (degree-gated slot-sum, bit-exact)
    {
        const float rr = rhos[LL - 1];
        float bel0 = bias[0], bel1 = bias[1];
        {
            float4 a = ((const float4*)s_cM)[t];
            float4 c4 = ((const float4*)s_cM)[t + NT];
            bel0 += (a.x + a.y) + (a.z + a.w);
            bel1 += (c4.x + c4.y) + (c4.z + c4.w);
        }
        if (deg0 > 4) {
            float4 a = ((const float4*)s_cM)[NN + t];
            bel0 += (a.x + a.y) + (a.z + a.w);
        }
        if (deg1 > 4) {
            float4 c4 = ((const float4*)s_cM)[NN + t + NT];
            bel1 += (c4.x + c4.y) + (c4.z + c4.w);
        }
        if (deg0 > 8) {
            float4 a = ((const float4*)s_cM)[2 * NN + t];
            bel0 += (a.x + a.y) + (a.z + a.w);
        }
        if (deg1 > 8) {
            float4 c4 = ((const float4*)s_cM)[2 * NN + t + NT];
            bel1 += (c4.x + c4.y) + (c4.z + c4.w);
        }
        float sp0 = fmaxf(bel0, 0.0f) + __logf(1.0f + __expf(-fabsf(bel0)));
        float sp1 = fmaxf(bel1, 0.0f) + __logf(1.0f + __expf(-fabsf(bel1)));
        loss += rr * ((sp0 - omeg[0] * bel0) + (sp1 - omeg[1] * bel1));
    }

    // ---- block-wide loss reduction (12 waves) ----
    #pragma unroll
    for (int off = 32; off > 0; off >>= 1)
        loss += __shfl_down(loss, off, 64);
    int wave = t >> 6, lane = t & 63;
    if (lane == 0) s_red[wave] = loss;
    __syncthreads();
    if (t == 0) {
        float tot = 0.0f;
        #pragma unroll
        for (int w = 0; w < 12; ++w) tot += s_red[w];
        atomicAdd(out, tot * (1.0f / (float)MB));
    }
}

// ---------------------------------------------------------------------------
extern "C" void kernel_launch(void* const* d_in, const int* in_sizes, int n_in,
                              void* d_out, int out_size, void* d_ws, size_t ws_size,
                              hipStream_t stream) {
    const float* synd     = (const float*)d_in[0];
    const float* errors   = (const float*)d_in[1];
    const float* H        = (const float*)d_in[2];
    const float* llrs     = (const float*)d_in[3];
    const float* w_de     = (const float*)d_in[4];
    const float* w_llr    = (const float*)d_in[5];
    const float* marg_de  = (const float*)d_in[6];
    const float* marg_llr = (const float*)d_in[7];
    const float* res_w    = (const float*)d_in[8];
    const float* rhos     = (const float*)d_in[9];
    float* out = (float*)d_out;

    float* wde_e   = (float*)d_ws;
    float* base_e  = wde_e + (size_t)LL * NE;
    float* marg_e  = base_e + (size_t)LL * NE;
    int*   gcnt    = (int*)(marg_e + NE);
    int*   col_pack= (int*)(gcnt + NN);

    hipMemsetAsync(gcnt, 0, NN * sizeof(int), stream);
    setup_kernel<<<MM, 256, 0, stream>>>(H, llrs, w_llr, w_de, marg_de,
                                         col_pack, base_e, wde_e, marg_e,
                                         gcnt, out);
    bp_kernel<<<MB, NT, 0, stream>>>(synd, errors, llrs, marg_llr, res_w, rhos,
                                     col_pack, base_e, wde_e, marg_e, gcnt, out);
}